// Round 4
// baseline (240.509 us; speedup 1.0000x reference)
//
#include <hip/hip_runtime.h>

// SpikingCell recurrence, dead-code-eliminated (absmax=0 verified R0/R1/R3):
//   dvi = (refrac >= 2) ? buf : 0
//   v += dvi; o = (v >= 1); v -= o
//   refrac = o ? 0 : refrac + 1
//   buf = x[b,t,n]
//
// R3 post-mortem: float4 + 64-thread blocks + fully-unrolled outer loop
// passed call 1 (absmax 0) but diverged on all later launches — cause
// unidentified; R4 removes the two deltas vs known-good rounds
// (128-thread workgroups, '#pragma unroll 1' outer loop) and keeps the
// float4 burst-size experiment: 1 KB dwordx4 wave-bursts vs R0/R1's
// 256-512 B, which is the leading theory for the 3.2 vs 6.3 TB/s gap.

constexpr int B = 16;
constexpr int T = 256;
constexpr int N = 8192;
constexpr int U = 8;       // pipeline depth in t-steps
constexpr int C4 = N / 4;  // float4 columns per batch row = 2048

__global__ __launch_bounds__(128) void spiking_kernel(
    const float4* __restrict__ x, float4* __restrict__ out) {
  const int gid = blockIdx.x * 128 + threadIdx.x;  // 0 .. B*C4-1
  const int b = gid / C4;
  const int n4 = gid - b * C4;

  const float4* __restrict__ xp = x + (size_t)b * T * C4 + n4;
  float4* __restrict__ op = out + (size_t)b * T * C4 + n4;

  float v[4] = {0.f, 0.f, 0.f, 0.f};
  float refrac[4] = {0.f, 0.f, 0.f, 0.f};
  float buf[4] = {0.f, 0.f, 0.f, 0.f};

  float4 cur[U], nxt[U];

#pragma unroll
  for (int u = 0; u < U; ++u) cur[u] = xp[(size_t)u * C4];

#pragma unroll 1
  for (int g = 0; g < T / U - 1; ++g) {
    const size_t base_next = (size_t)(g + 1) * U * C4;
#pragma unroll
    for (int u = 0; u < U; ++u) nxt[u] = xp[base_next + (size_t)u * C4];

    const size_t base_cur = (size_t)g * U * C4;
#pragma unroll
    for (int u = 0; u < U; ++u) {
      const float xa[4] = {cur[u].x, cur[u].y, cur[u].z, cur[u].w};
      float o[4];
#pragma unroll
      for (int j = 0; j < 4; ++j) {
        const float dvi = (refrac[j] >= 2.0f) ? buf[j] : 0.0f;
        v[j] += dvi;
        o[j] = (v[j] >= 1.0f) ? 1.0f : 0.0f;
        v[j] -= o[j];
        refrac[j] = (o[j] == 0.0f) ? (refrac[j] + 1.0f) : 0.0f;
        buf[j] = xa[j];
      }
      op[base_cur + (size_t)u * C4] = make_float4(o[0], o[1], o[2], o[3]);
    }

#pragma unroll
    for (int u = 0; u < U; ++u) cur[u] = nxt[u];
  }

  // Epilogue: last U timesteps.
  const size_t base_last = (size_t)(T - U) * C4;
#pragma unroll
  for (int u = 0; u < U; ++u) {
    const float xa[4] = {cur[u].x, cur[u].y, cur[u].z, cur[u].w};
    float o[4];
#pragma unroll
    for (int j = 0; j < 4; ++j) {
      const float dvi = (refrac[j] >= 2.0f) ? buf[j] : 0.0f;
      v[j] += dvi;
      o[j] = (v[j] >= 1.0f) ? 1.0f : 0.0f;
      v[j] -= o[j];
      refrac[j] = (o[j] == 0.0f) ? (refrac[j] + 1.0f) : 0.0f;
      buf[j] = xa[j];
    }
    op[base_last + (size_t)u * C4] = make_float4(o[0], o[1], o[2], o[3]);
  }
}

extern "C" void kernel_launch(void* const* d_in, const int* in_sizes, int n_in,
                              void* d_out, int out_size, void* d_ws,
                              size_t ws_size, hipStream_t stream) {
  const float4* x = (const float4*)d_in[0];
  float4* out = (float4*)d_out;

  const int threads = 128;
  const int total = B * C4;            // one thread per float4 column
  const int blocks = total / threads;  // 256 blocks -> 1 block/CU, 2 waves/CU
  spiking_kernel<<<blocks, threads, 0, stream>>>(x, out);
}

// Round 5
// 237.660 us; speedup vs baseline: 1.0120x; 1.0120x over previous
//
#include <hip/hip_runtime.h>
#include <stdint.h>

// SpikingCell recurrence, dead-code-eliminated (absmax=0 verified R0/R1/R4):
//   dvi = (refrac >= 2) ? buf : 0
//   v += dvi; o = (v >= 1); v -= o
//   refrac = o ? 0 : refrac + 1
//   buf = x[b,t,n]
//
// R4 post-mortem: ~85 us regardless of burst size (256B/512B/1KB) and
// waves/CU (2 vs 8) -> compiler caps per-wave outstanding loads; register
// pipelines collapse. R5: hardware-queued prefetch via global_load_lds
// (size=4), 16 t-steps staged per chunk, ping-pong between two STATIC
// __shared__ arrays (constant addresses so AA can separate next-chunk DMA
// from current-chunk ds_read). Per-wave self-consumption -> no barriers.

constexpr int B = 16;
constexpr int T = 256;
constexpr int N = 8192;
constexpr int CH = 16;    // timesteps per staged chunk
constexpr int BLK = 256;  // threads per block
constexpr int NG = T / CH;  // 16 chunks

typedef __attribute__((address_space(3))) uint32_t lds_u32;
typedef __attribute__((address_space(1))) const uint32_t glb_u32;

__global__ __launch_bounds__(BLK) void spiking_kernel(
    const float* __restrict__ x, float* __restrict__ out) {
  __shared__ float sA[CH][BLK];
  __shared__ float sB[CH][BLK];

  const int tid = threadIdx.x;
  const int gid = blockIdx.x * BLK + tid;  // 0 .. B*N-1
  const int b = gid >> 13;                 // gid / N
  const int n = gid & (N - 1);
  const int wbase = (tid >> 6) * 64;       // wave-uniform lane-0 offset

  const float* __restrict__ xp = x + (size_t)b * T * N + n;  // per-lane
  float* __restrict__ op = out + (size_t)b * T * N + n;

  float v = 0.f, refrac = 0.f, buf = 0.f;

  // Stage chunk 0 into sA (async DMA, one 256 B burst per wave per t).
#pragma unroll
  for (int u = 0; u < CH; ++u) {
    __builtin_amdgcn_global_load_lds((glb_u32*)(xp + (size_t)u * N),
                                     (lds_u32*)&sA[u][wbase], 4, 0, 0);
  }

#pragma unroll 1
  for (int g = 0; g < NG; g += 2) {
    // ---- stage chunk g+1 into sB ----
    {
      const size_t tb = (size_t)(g + 1) * CH;
#pragma unroll
      for (int u = 0; u < CH; ++u) {
        __builtin_amdgcn_global_load_lds((glb_u32*)(xp + (tb + u) * N),
                                         (lds_u32*)&sB[u][wbase], 4, 0, 0);
      }
    }
    // ---- consume chunk g from sA ----
    {
      const size_t ob = (size_t)g * CH;
#pragma unroll
      for (int u = 0; u < CH; ++u) {
        const float xt = sA[u][tid];
        const float dvi = (refrac >= 2.0f) ? buf : 0.0f;
        v += dvi;
        const float o = (v >= 1.0f) ? 1.0f : 0.0f;
        v -= o;
        refrac = (o == 0.0f) ? (refrac + 1.0f) : 0.0f;
        buf = xt;
        op[(ob + u) * N] = o;
      }
    }
    // ---- stage chunk g+2 into sA (skip on last pair) ----
    if (g + 2 < NG) {
      const size_t tb = (size_t)(g + 2) * CH;
#pragma unroll
      for (int u = 0; u < CH; ++u) {
        __builtin_amdgcn_global_load_lds((glb_u32*)(xp + (tb + u) * N),
                                         (lds_u32*)&sA[u][wbase], 4, 0, 0);
      }
    }
    // ---- consume chunk g+1 from sB ----
    {
      const size_t ob = (size_t)(g + 1) * CH;
#pragma unroll
      for (int u = 0; u < CH; ++u) {
        const float xt = sB[u][tid];
        const float dvi = (refrac >= 2.0f) ? buf : 0.0f;
        v += dvi;
        const float o = (v >= 1.0f) ? 1.0f : 0.0f;
        v -= o;
        refrac = (o == 0.0f) ? (refrac + 1.0f) : 0.0f;
        buf = xt;
        op[(ob + u) * N] = o;
      }
    }
  }
}

extern "C" void kernel_launch(void* const* d_in, const int* in_sizes, int n_in,
                              void* d_out, int out_size, void* d_ws,
                              size_t ws_size, hipStream_t stream) {
  const float* x = (const float*)d_in[0];
  float* out = (float*)d_out;

  const int total = B * N;           // one thread per element
  const int blocks = total / BLK;    // 512 blocks -> 2 blocks/CU, 8 waves/CU
  spiking_kernel<<<blocks, BLK, 0, stream>>>(x, out);
}

// Round 6
// 223.134 us; speedup vs baseline: 1.0779x; 1.0651x over previous
//
#include <hip/hip_runtime.h>

// SpikingCell recurrence, dead-code-eliminated (absmax=0 verified R0/R1/R4/R5):
//   dvi = (refrac >= 2) ? buf : 0
//   v += dvi; o = (v >= 1); v -= o
//   refrac = o ? 0 : refrac + 1
//   buf = x[b,t,n]
//
// R5 post-mortem: five structures (scalar/float2/float4, register pipelines,
// LDS-DMA ping-pong, 2..8 waves/CU) ALL land at 82-87 us ~ 3.2 TB/s
// effective. Burst size, wave count, prefetch mechanism: invariant.
// Remaining theory: the 32 KB-strided read+write pattern itself caps the
// memory system (DRAM page misses + rd/wr turnaround + L2 write-allocate
// interference). R6 tests the last lever: nontemporal loads+stores to keep
// the streaming data out of L1/L2 allocation, on the known-good R1 skeleton.

constexpr int B = 16;
constexpr int T = 256;
constexpr int N = 8192;
constexpr int U = 8;  // pipeline group size

__global__ __launch_bounds__(256, 2) void spiking_kernel(
    const float* __restrict__ x, float* __restrict__ out) {
  const int c = blockIdx.x * blockDim.x + threadIdx.x;  // 0 .. B*N-1
  const int b = c >> 13;      // c / N
  const int n = c & (N - 1);  // c % N

  const float* __restrict__ xp = x + (size_t)b * T * N + n;
  float* __restrict__ op = out + (size_t)b * T * N + n;

  float v = 0.f, refrac = 0.f, buf = 0.f;

  float cur[U], nxt[U];

#pragma unroll
  for (int u = 0; u < U; ++u)
    cur[u] = __builtin_nontemporal_load(xp + (size_t)u * N);

#pragma unroll 1
  for (int g = 0; g < T / U - 1; ++g) {
    const size_t base_next = (size_t)(g + 1) * U * N;
#pragma unroll
    for (int u = 0; u < U; ++u)
      nxt[u] = __builtin_nontemporal_load(xp + base_next + (size_t)u * N);

    const size_t base_cur = (size_t)g * U * N;
#pragma unroll
    for (int u = 0; u < U; ++u) {
      const float dvi = (refrac >= 2.0f) ? buf : 0.0f;
      v += dvi;
      const float o = (v >= 1.0f) ? 1.0f : 0.0f;
      v -= o;
      refrac = (o == 0.0f) ? (refrac + 1.0f) : 0.0f;
      buf = cur[u];
      __builtin_nontemporal_store(o, op + base_cur + (size_t)u * N);
    }

#pragma unroll
    for (int u = 0; u < U; ++u) cur[u] = nxt[u];
  }

  // Epilogue: last U timesteps.
  const size_t base_last = (size_t)(T - U) * N;
#pragma unroll
  for (int u = 0; u < U; ++u) {
    const float dvi = (refrac >= 2.0f) ? buf : 0.0f;
    v += dvi;
    const float o = (v >= 1.0f) ? 1.0f : 0.0f;
    v -= o;
    refrac = (o == 0.0f) ? (refrac + 1.0f) : 0.0f;
    buf = cur[u];
    __builtin_nontemporal_store(o, op + base_last + (size_t)u * N);
  }
}

extern "C" void kernel_launch(void* const* d_in, const int* in_sizes, int n_in,
                              void* d_out, int out_size, void* d_ws,
                              size_t ws_size, hipStream_t stream) {
  const float* x = (const float*)d_in[0];
  float* out = (float*)d_out;

  const int threads = 256;
  const int total = B * N;             // one thread per element
  const int blocks = total / threads;  // 512 blocks -> 2 blocks/CU, 8 waves/CU
  spiking_kernel<<<blocks, threads, 0, stream>>>(x, out);
}